// Round 4
// baseline (7656.644 us; speedup 1.0000x reference)
//
#include <hip/hip_runtime.h>
#include <hip/hip_bf16.h>
#include <cstdint>
#include <cstddef>

// ---------------- model dims ----------------
#define B_SZ    2048
#define H_SZ    512
#define G4      2048      // 4*H
#define TSTEPS  21
#define MAXLEN  1000
#define KIH     1024      // padded input-K (layer0: 1000->1024 ; layer1: 2H=1024)
#define KCAT    1536      // KIH + H_SZ
#define NCLS    10

// ---------------- GEMM tile ----------------
#define BM 128
#define BN 128
#define BK 32

typedef short bf16x8 __attribute__((ext_vector_type(8)));            // 8 bf16 (4 VGPRs)
typedef float f32x4  __attribute__((ext_vector_type(4)));
typedef unsigned short ushort8 __attribute__((ext_vector_type(8)));  // 16B vector

__device__ __forceinline__ unsigned short f2bf(float f) {
  __hip_bfloat16 h = __float2bfloat16(f);
  unsigned short u;
  __builtin_memcpy(&u, &h, sizeof(u));
  return u;
}
__device__ __forceinline__ float bf2f(unsigned short u) {
  __hip_bfloat16 h;
  __builtin_memcpy(&h, &u, sizeof(h));
  return __bfloat162float(h);
}

__device__ __forceinline__ float sigmoidf_(float x) {
  x = fminf(fmaxf(x, -30.f), 30.f);
  return 1.f / (1.f + __expf(-x));
}
__device__ __forceinline__ float tanhf_(float x) {
  float xc = fminf(fmaxf(x, -15.f), 15.f);
  float e = __expf(2.f * xc);
  return (e - 1.f) / (e + 1.f);
}

// ============================================================
// prep: pack B[d][p][c] = [W_ih (padded to KIH) | W_hh], rows permuted,
// SPLIT into bf16 hi + lo (w ≈ hi + lo, ~16 mantissa bits).
// p = 4*j + type  <->  orig gate row r = type*512 + j   (i,f,g,o order)
// Inputs are FLOAT32 (per reference dtypes).
// ============================================================
__global__ void prep_w_kernel(const float* __restrict__ w_ih0,
                              const float* __restrict__ w_hh0,
                              const float* __restrict__ w_ih1,
                              const float* __restrict__ w_hh1,
                              unsigned short* __restrict__ Bhi0,
                              unsigned short* __restrict__ Blo0,
                              unsigned short* __restrict__ Bhi1,
                              unsigned short* __restrict__ Blo1) {
  size_t idx = (size_t)blockIdx.x * blockDim.x + threadIdx.x;
  const size_t total = (size_t)2 * G4 * KCAT;
  if (idx >= total) return;
  int cc = (int)(idx % KCAT);
  size_t rowidx = idx / KCAT;          // d*G4 + p
  int p  = (int)(rowidx % G4);
  int dd = (int)(rowidx / G4);
  int j  = p >> 2;
  int ty = p & 3;
  size_t rbase = (size_t)dd * G4 + (size_t)(ty * H_SZ + j);

  float w0;
  if (cc < MAXLEN)      w0 = w_ih0[rbase * MAXLEN + cc];
  else if (cc < KIH)    w0 = 0.f;                             // zero pad 1000..1023
  else                  w0 = w_hh0[rbase * H_SZ + (cc - KIH)];
  unsigned short h0 = f2bf(w0);
  Bhi0[idx] = h0;
  Blo0[idx] = f2bf(w0 - bf2f(h0));

  float w1;
  if (cc < KIH)         w1 = w_ih1[rbase * KIH + cc];
  else                  w1 = w_hh1[rbase * H_SZ + (cc - KIH)];
  unsigned short h1 = f2bf(w1);
  Bhi1[idx] = h1;
  Blo1[idx] = f2bf(w1 - bf2f(h1));
}

__global__ void prep_b_kernel(const float* __restrict__ b_ih0,
                              const float* __restrict__ b_hh0,
                              const float* __restrict__ b_ih1,
                              const float* __restrict__ b_hh1,
                              float* __restrict__ bias0,
                              float* __restrict__ bias1) {
  int idx = blockIdx.x * blockDim.x + threadIdx.x;   // 0 .. 2*G4-1
  if (idx >= 2 * G4) return;
  int p  = idx % G4;
  int dd = idx / G4;
  int src = dd * G4 + (p & 3) * H_SZ + (p >> 2);
  bias0[idx] = b_ih0[src] + b_hh0[src];
  bias1[idx] = b_ih1[src] + b_hh1[src];
}

// ============================================================
// one recurrent step (both directions via blockIdx.z)
// gates = [A_in | h] @ (Bhi+Blo)[d]^T + bias ;  LSTM cell fused in epilogue
// LAYER 0: A_in[k] = onehot(x[b,k]==t) (k<KIH, exact in bf16); writes seq_out
// LAYER 1: A_in = seq_in[tcur] (bf16);  accumulates zacc += emb_w[tcur]*h (f32)
// ============================================================
template <int LAYER>
__global__ __launch_bounds__(256, 2)
void step_kernel(const int* __restrict__ x,
                 const unsigned short* __restrict__ seq_in,   // [T,B,2H] bf16
                 const unsigned short* __restrict__ Bhi,      // [2,G4,KCAT] bf16
                 const unsigned short* __restrict__ Blo,      // [2,G4,KCAT] bf16
                 const float* __restrict__ bias,              // [2,G4] f32
                 const unsigned short* __restrict__ h_in,     // [2,B,H] bf16
                 unsigned short* __restrict__ h_out,          // [2,B,H] bf16
                 float* __restrict__ c_st,                    // [2,B,H] f32
                 unsigned short* __restrict__ seq_out,        // [T,B,2H]   (LAYER 0)
                 float* __restrict__ zacc,                    // [B,2H] f32 (LAYER 1)
                 const float* __restrict__ emb_w,             // [21] f32   (LAYER 1)
                 int step) {
  __shared__ union {
    struct {
      unsigned short A[BM * BK];    // 8 KB
      unsigned short Bh[BN * BK];   // 8 KB
      unsigned short Bl[BN * BK];   // 8 KB
    } t;
    float gates[BM * 132];          // 67.6 KB
  } sm;

  const int tid  = threadIdx.x;
  const int lane = tid & 63;
  const int wave = tid >> 6;
  const int wr   = wave >> 1;
  const int wc   = wave & 1;
  const int q    = lane >> 4;
  const int r16  = lane & 15;

  const int d    = blockIdx.z;
  const int tcur = d ? (TSTEPS - 1 - step) : step;
  const int n0   = blockIdx.x * BN;   // permuted gate cols
  const int m0   = blockIdx.y * BM;   // batch rows

  const unsigned short* Bh_mat = Bhi + (size_t)d * G4 * KCAT;
  const unsigned short* Bl_mat = Blo + (size_t)d * G4 * KCAT;

  float bval[4];
#pragma unroll
  for (int nt = 0; nt < 4; ++nt)
    bval[nt] = bias[d * G4 + n0 + wc * 64 + nt * 16 + r16];

  f32x4 acc[4][4];
#pragma unroll
  for (int mt = 0; mt < 4; ++mt)
#pragma unroll
    for (int nt = 0; nt < 4; ++nt) {
      f32x4 z = {0.f, 0.f, 0.f, 0.f};
      acc[mt][nt] = z;
    }

  // staging decomposition: [128 rows][32 cols] = 512 chunks of 8 elts; 2/thread
  const int c0a = tid, c1a = 256 + tid;
  const int r0c = c0a >> 2, r1c = c1a >> 2;       // chunk rows
  const int o0c = (c0a & 3) * 8, o1c = (c1a & 3) * 8;  // chunk col offsets
  const int row_a = tid >> 1;                     // one-hot path: 2 threads/row
  const int seg_a = (tid & 1) * 16;

  for (int kt = 0; kt < KCAT / BK; ++kt) {
    const int k0 = kt * BK;

    // ---- global loads first (latency hiding) ----
    ushort8 bh0 = *(const ushort8*)(Bh_mat + (size_t)(n0 + r0c) * KCAT + k0 + o0c);
    ushort8 bh1 = *(const ushort8*)(Bh_mat + (size_t)(n0 + r1c) * KCAT + k0 + o1c);
    ushort8 bl0 = *(const ushort8*)(Bl_mat + (size_t)(n0 + r0c) * KCAT + k0 + o0c);
    ushort8 bl1 = *(const ushort8*)(Bl_mat + (size_t)(n0 + r1c) * KCAT + k0 + o1c);

    unsigned int pk[8];     // one-hot path payload
    ushort8 va0, va1;       // bf16 A path payload
    const bool onehot = (LAYER == 0) && (k0 < KIH);
    if (onehot) {
      const int* xr = x + (size_t)(m0 + row_a) * MAXLEN + k0 + seg_a;
#pragma unroll
      for (int e = 0; e < 8; ++e) {
        int kk = k0 + seg_a + 2 * e;
        int v0 = (kk < MAXLEN) ? xr[2 * e] : -1;
        int v1 = (kk + 1 < MAXLEN) ? xr[2 * e + 1] : -1;
        unsigned int lo = (v0 == tcur) ? 0x3F80u : 0u;   // bf16 1.0
        unsigned int hi = (v1 == tcur) ? 0x3F80u : 0u;
        pk[e] = lo | (hi << 16);
      }
    } else {
      const unsigned short* Asrc;
      int lda, kof;
      if (LAYER == 1 && k0 < KIH) {
        Asrc = seq_in + (size_t)tcur * B_SZ * (2 * H_SZ);
        lda = 2 * H_SZ; kof = k0;
      } else {
        Asrc = h_in + (size_t)d * B_SZ * H_SZ;
        lda = H_SZ; kof = k0 - KIH;
      }
      va0 = *(const ushort8*)(Asrc + (size_t)(m0 + r0c) * lda + kof + o0c);
      va1 = *(const ushort8*)(Asrc + (size_t)(m0 + r1c) * lda + kof + o1c);
    }

    __syncthreads();   // previous iteration's MFMA LDS reads complete

    if (onehot) {
      unsigned int* lw = (unsigned int*)(sm.t.A + row_a * BK + seg_a);
      *(uint4*)lw       = make_uint4(pk[0], pk[1], pk[2], pk[3]);
      *(uint4*)(lw + 4) = make_uint4(pk[4], pk[5], pk[6], pk[7]);
    } else {
      *(ushort8*)(sm.t.A + r0c * BK + o0c) = va0;
      *(ushort8*)(sm.t.A + r1c * BK + o1c) = va1;
    }
    *(ushort8*)(sm.t.Bh + r0c * BK + o0c) = bh0;
    *(ushort8*)(sm.t.Bh + r1c * BK + o1c) = bh1;
    *(ushort8*)(sm.t.Bl + r0c * BK + o0c) = bl0;
    *(ushort8*)(sm.t.Bl + r1c * BK + o1c) = bl1;
    __syncthreads();

    // ---- MFMA: 4x4 16x16 tiles per wave, 2 products (B hi+lo split) ----
    // A/B fragment: m/n = lane&15, k = (lane>>4)*8 + j   [m89/m91 verified]
    bf16x8 af[4], bh[4], bl[4];
#pragma unroll
    for (int mt = 0; mt < 4; ++mt)
      af[mt] = *(const bf16x8*)(sm.t.A + (wr * 64 + mt * 16 + r16) * BK + q * 8);
#pragma unroll
    for (int nt = 0; nt < 4; ++nt) {
      bh[nt] = *(const bf16x8*)(sm.t.Bh + (wc * 64 + nt * 16 + r16) * BK + q * 8);
      bl[nt] = *(const bf16x8*)(sm.t.Bl + (wc * 64 + nt * 16 + r16) * BK + q * 8);
    }
#pragma unroll
    for (int mt = 0; mt < 4; ++mt)
#pragma unroll
      for (int nt = 0; nt < 4; ++nt) {
        acc[mt][nt] = __builtin_amdgcn_mfma_f32_16x16x32_bf16(af[mt], bh[nt], acc[mt][nt], 0, 0, 0);
        acc[mt][nt] = __builtin_amdgcn_mfma_f32_16x16x32_bf16(af[mt], bl[nt], acc[mt][nt], 0, 0, 0);
      }
  }
  __syncthreads();   // all MFMA LDS reads done before gates overwrite

  // ---- epilogue: gates (+bias) -> LDS ----
  // C/D layout: col = lane&15, row = (lane>>4)*4 + reg   [m89/m91 verified]
#pragma unroll
  for (int mt = 0; mt < 4; ++mt)
#pragma unroll
    for (int nt = 0; nt < 4; ++nt)
#pragma unroll
      for (int r = 0; r < 4; ++r) {
        int ml = wr * 64 + mt * 16 + q * 4 + r;
        int nl = wc * 64 + nt * 16 + r16;
        sm.gates[ml * 132 + nl] = acc[mt][nt][r] + bval[nt];
      }
  __syncthreads();

  // ---- LSTM cell: permuted cols give (i,f,g,o) as consecutive quads ----
  const int jbase = blockIdx.x * 32;   // 32 hidden units per N-tile
  const float ew = (LAYER == 1) ? emb_w[tcur] : 0.f;
#pragma unroll
  for (int it = 0; it < 16; ++it) {
    int cell = it * 256 + tid;         // 0..4095 = 128 b x 32 j
    int rl = cell >> 5;
    int jl = cell & 31;
    const float4 g = *(const float4*)(&sm.gates[rl * 132 + jl * 4]);
    float si = sigmoidf_(g.x);
    float sf = sigmoidf_(g.y);
    float tg = tanhf_(g.z);
    float so = sigmoidf_(g.w);
    int b = m0 + rl;
    int j = jbase + jl;
    size_t cidx = ((size_t)d * B_SZ + b) * H_SZ + j;
    float cn = sf * c_st[cidx] + si * tg;
    float hv = so * tanhf_(cn);
    c_st[cidx] = cn;
    h_out[cidx] = f2bf(hv);
    if (LAYER == 0) {
      seq_out[((size_t)tcur * B_SZ + b) * (2 * H_SZ) + d * H_SZ + j] = f2bf(hv);
    } else {
      // emb contraction fused (full-precision h into the z accumulator)
      zacc[(size_t)b * (2 * H_SZ) + d * H_SZ + j] += ew * hv;
    }
  }
}

// ============================================================
// final: z[b,:] = zacc[b,:] + emb_b ; out = z @ fc_w^T + fc_b   (all f32)
// ============================================================
__global__ __launch_bounds__(256)
void final_kernel(const float* __restrict__ zacc,    // [B, 2H] f32
                  const float* __restrict__ emb_b,   // [1]
                  const float* __restrict__ fc_w,    // [10, 2H]
                  const float* __restrict__ fc_b,    // [10]
                  float* __restrict__ out) {         // [B, 10] f32
  const int b = blockIdx.x;
  const int tid = threadIdx.x;
  const int c0 = tid * 4;

  const float zb = emb_b[0];
  const float4 z4 = *(const float4*)(zacc + (size_t)b * (2 * H_SZ) + c0);
  float z0 = z4.x + zb, z1 = z4.y + zb, z2 = z4.z + zb, z3 = z4.w + zb;

  float part[NCLS];
#pragma unroll
  for (int nc = 0; nc < NCLS; ++nc) {
    const float4 f = *(const float4*)(fc_w + (size_t)nc * (2 * H_SZ) + c0);
    part[nc] = z0 * f.x + z1 * f.y + z2 * f.z + z3 * f.w;
  }
#pragma unroll
  for (int nc = 0; nc < NCLS; ++nc)
#pragma unroll
    for (int off2 = 32; off2 > 0; off2 >>= 1)
      part[nc] += __shfl_down(part[nc], off2);

  __shared__ float red[4][NCLS];
  if ((tid & 63) == 0) {
#pragma unroll
    for (int nc = 0; nc < NCLS; ++nc) red[tid >> 6][nc] = part[nc];
  }
  __syncthreads();
  if (tid < NCLS) {
    float s = red[0][tid] + red[1][tid] + red[2][tid] + red[3][tid] + fc_b[tid];
    out[b * NCLS + tid] = s;
  }
}

// ============================================================
extern "C" void kernel_launch(void* const* d_in, const int* in_sizes, int n_in,
                              void* d_out, int out_size, void* d_ws, size_t ws_size,
                              hipStream_t stream) {
  (void)in_sizes; (void)n_in; (void)out_size; (void)ws_size;

  const int*   x     = (const int*)d_in[0];
  const float* w_ih0 = (const float*)d_in[1];
  const float* w_hh0 = (const float*)d_in[2];
  const float* b_ih0 = (const float*)d_in[3];
  const float* b_hh0 = (const float*)d_in[4];
  const float* w_ih1 = (const float*)d_in[5];
  const float* w_hh1 = (const float*)d_in[6];
  const float* b_ih1 = (const float*)d_in[7];
  const float* b_hh1 = (const float*)d_in[8];
  const float* emb_w = (const float*)d_in[9];
  const float* emb_b = (const float*)d_in[10];
  const float* fc_w  = (const float*)d_in[11];
  const float* fc_b  = (const float*)d_in[12];

  // -------- workspace layout (~165 MB) --------
  char* ws = (char*)d_ws;
  size_t off = 0;
  auto alloc = [&](size_t bytes) -> void* {
    void* p = ws + off;
    off += (bytes + 255) & ~(size_t)255;
    return p;
  };
  const size_t bmat_b = (size_t)2 * G4 * KCAT * 2;              // 12.6 MB each
  const size_t h_b    = (size_t)2 * B_SZ * H_SZ * 2;            // 4.2 MB
  const size_t c_b    = (size_t)2 * B_SZ * H_SZ * 4;            // 8.4 MB
  const size_t seq_b  = (size_t)TSTEPS * B_SZ * (2 * H_SZ) * 2; // 88 MB
  const size_t z_b    = (size_t)B_SZ * (2 * H_SZ) * 4;          // 8.4 MB

  unsigned short* Bhi0 = (unsigned short*)alloc(bmat_b);
  unsigned short* Blo0 = (unsigned short*)alloc(bmat_b);
  unsigned short* Bhi1 = (unsigned short*)alloc(bmat_b);
  unsigned short* Blo1 = (unsigned short*)alloc(bmat_b);
  float*          bias0 = (float*)alloc((size_t)2 * G4 * 4);
  float*          bias1 = (float*)alloc((size_t)2 * G4 * 4);
  unsigned short* hA    = (unsigned short*)alloc(h_b);
  unsigned short* hB    = (unsigned short*)alloc(h_b);
  float*          cst   = (float*)alloc(c_b);
  float*          zacc  = (float*)alloc(z_b);
  unsigned short* seq0  = (unsigned short*)alloc(seq_b);

  // -------- prep --------
  {
    size_t total = (size_t)2 * G4 * KCAT;
    int blocks = (int)((total + 255) / 256);
    prep_w_kernel<<<blocks, 256, 0, stream>>>(w_ih0, w_hh0, w_ih1, w_hh1,
                                              Bhi0, Blo0, Bhi1, Blo1);
    prep_b_kernel<<<16, 256, 0, stream>>>(b_ih0, b_hh0, b_ih1, b_hh1, bias0, bias1);
  }

  dim3 grid(G4 / BN, B_SZ / BM, 2);   // (16, 16, 2)

  // -------- layer 0 --------
  hipMemsetAsync(hA, 0, h_b, stream);
  hipMemsetAsync(cst, 0, c_b, stream);
  for (int s = 0; s < TSTEPS; ++s) {
    const unsigned short* hin  = (s & 1) ? hB : hA;
    unsigned short*       hout = (s & 1) ? hA : hB;
    step_kernel<0><<<grid, 256, 0, stream>>>(x, nullptr, Bhi0, Blo0, bias0, hin, hout, cst,
                                             seq0, nullptr, nullptr, s);
  }

  // -------- layer 1 (emb contraction fused into epilogue) --------
  hipMemsetAsync(hA, 0, h_b, stream);
  hipMemsetAsync(cst, 0, c_b, stream);
  hipMemsetAsync(zacc, 0, z_b, stream);
  for (int s = 0; s < TSTEPS; ++s) {
    const unsigned short* hin  = (s & 1) ? hB : hA;
    unsigned short*       hout = (s & 1) ? hA : hB;
    step_kernel<1><<<grid, 256, 0, stream>>>(nullptr, seq0, Bhi1, Blo1, bias1, hin, hout, cst,
                                             nullptr, zacc, emb_w, s);
  }

  // -------- fc --------
  final_kernel<<<B_SZ, 256, 0, stream>>>(zacc, emb_b, fc_w, fc_b, (float*)d_out);
}

// Round 5
// 6988.082 us; speedup vs baseline: 1.0957x; 1.0957x over previous
//
#include <hip/hip_runtime.h>
#include <hip/hip_bf16.h>
#include <cstdint>
#include <cstddef>

// ---------------- model dims ----------------
#define B_SZ    2048
#define H_SZ    512
#define G4      2048      // 4*H
#define TSTEPS  21
#define MAXLEN  1000
#define KIH     1024      // padded input-K (layer0: 1000->1024 ; layer1: 2H=1024)
#define KCAT    1536      // KIH + H_SZ
#define NCLS    10

// ---------------- GEMM tile ----------------
#define BM 128
#define BN 128
#define BK 32
#define LDSK 40           // padded LDS K-stride (elements): 80 B rows -> 2-way banks (free)
#define GPAD 33           // gates chunk stride (floats)

typedef short bf16x8 __attribute__((ext_vector_type(8)));            // 8 bf16 (4 VGPRs)
typedef float f32x4  __attribute__((ext_vector_type(4)));
typedef unsigned short ushort8 __attribute__((ext_vector_type(8)));  // 16B vector

__device__ __forceinline__ unsigned short f2bf(float f) {
  __hip_bfloat16 h = __float2bfloat16(f);
  unsigned short u;
  __builtin_memcpy(&u, &h, sizeof(u));
  return u;
}
__device__ __forceinline__ float bf2f(unsigned short u) {
  __hip_bfloat16 h;
  __builtin_memcpy(&h, &u, sizeof(h));
  return __bfloat162float(h);
}

__device__ __forceinline__ float sigmoidf_(float x) {
  x = fminf(fmaxf(x, -30.f), 30.f);
  return 1.f / (1.f + __expf(-x));
}
__device__ __forceinline__ float tanhf_(float x) {
  float xc = fminf(fmaxf(x, -15.f), 15.f);
  float e = __expf(2.f * xc);
  return (e - 1.f) / (e + 1.f);
}

// ============================================================
// prep: pack B[d][p][c] = [W_ih (padded to KIH) | W_hh], rows permuted,
// SPLIT into bf16 hi + lo (w ≈ hi + lo, ~16 mantissa bits).
// p = 4*j + type  <->  orig gate row r = type*512 + j   (i,f,g,o order)
// ============================================================
__global__ void prep_w_kernel(const float* __restrict__ w_ih0,
                              const float* __restrict__ w_hh0,
                              const float* __restrict__ w_ih1,
                              const float* __restrict__ w_hh1,
                              unsigned short* __restrict__ Bhi0,
                              unsigned short* __restrict__ Blo0,
                              unsigned short* __restrict__ Bhi1,
                              unsigned short* __restrict__ Blo1) {
  size_t idx = (size_t)blockIdx.x * blockDim.x + threadIdx.x;
  const size_t total = (size_t)2 * G4 * KCAT;
  if (idx >= total) return;
  int cc = (int)(idx % KCAT);
  size_t rowidx = idx / KCAT;          // d*G4 + p
  int p  = (int)(rowidx % G4);
  int dd = (int)(rowidx / G4);
  int j  = p >> 2;
  int ty = p & 3;
  size_t rbase = (size_t)dd * G4 + (size_t)(ty * H_SZ + j);

  float w0;
  if (cc < MAXLEN)      w0 = w_ih0[rbase * MAXLEN + cc];
  else if (cc < KIH)    w0 = 0.f;                             // zero pad 1000..1023
  else                  w0 = w_hh0[rbase * H_SZ + (cc - KIH)];
  unsigned short h0 = f2bf(w0);
  Bhi0[idx] = h0;
  Blo0[idx] = f2bf(w0 - bf2f(h0));

  float w1;
  if (cc < KIH)         w1 = w_ih1[rbase * KIH + cc];
  else                  w1 = w_hh1[rbase * H_SZ + (cc - KIH)];
  unsigned short h1 = f2bf(w1);
  Bhi1[idx] = h1;
  Blo1[idx] = f2bf(w1 - bf2f(h1));
}

__global__ void prep_b_kernel(const float* __restrict__ b_ih0,
                              const float* __restrict__ b_hh0,
                              const float* __restrict__ b_ih1,
                              const float* __restrict__ b_hh1,
                              float* __restrict__ bias0,
                              float* __restrict__ bias1) {
  int idx = blockIdx.x * blockDim.x + threadIdx.x;   // 0 .. 2*G4-1
  if (idx >= 2 * G4) return;
  int p  = idx % G4;
  int dd = idx / G4;
  int src = dd * G4 + (p & 3) * H_SZ + (p >> 2);
  bias0[idx] = b_ih0[src] + b_hh0[src];
  bias1[idx] = b_ih1[src] + b_hh1[src];
}

// ============================================================
// one recurrent step (both directions via blockIdx.z)
// 512 threads = 8 waves (4 wr x 2 wc); each wave: 2 M-tiles x 4 N-tiles.
// gates = [A_in | h] @ (Bhi+Blo)[d]^T + bias ;  LSTM cell fused in epilogue
// ============================================================
template <int LAYER>
__global__ __launch_bounds__(512, 4)
void step_kernel(const int* __restrict__ x,
                 const unsigned short* __restrict__ seq_in,   // [T,B,2H] bf16
                 const unsigned short* __restrict__ Bhi,      // [2,G4,KCAT] bf16
                 const unsigned short* __restrict__ Blo,      // [2,G4,KCAT] bf16
                 const float* __restrict__ bias,              // [2,G4] f32
                 const unsigned short* __restrict__ h_in,     // [2,B,H] bf16
                 unsigned short* __restrict__ h_out,          // [2,B,H] bf16
                 float* __restrict__ c_st,                    // [2,B,H] f32
                 unsigned short* __restrict__ seq_out,        // [T,B,2H]   (LAYER 0)
                 float* __restrict__ zacc,                    // [B,2H] f32 (LAYER 1)
                 const float* __restrict__ emb_w,             // [21] f32   (LAYER 1)
                 int step) {
  __shared__ union {
    struct {
      unsigned short A[BM * LDSK];    // 10 KB
      unsigned short Bh[BN * LDSK];   // 10 KB
      unsigned short Bl[BN * LDSK];   // 10 KB
    } t;
    float gc[BM * GPAD];              // 16.9 KB gates chunk (128 x 32 + pad)
  } sm;                               // union: 30 KB

  const int tid  = threadIdx.x;
  const int lane = tid & 63;
  const int wave = tid >> 6;          // 0..7
  const int wr   = wave >> 1;         // 0..3  (M: wr*32 + mt*16)
  const int wc   = wave & 1;          // 0..1  (N: wc*64 + nt*16)
  const int q    = lane >> 4;
  const int r16  = lane & 15;

  const int d    = blockIdx.z;
  const int tcur = d ? (TSTEPS - 1 - step) : step;
  const int n0   = blockIdx.x * BN;   // permuted gate cols
  const int m0   = blockIdx.y * BM;   // batch rows

  const unsigned short* Bh_mat = Bhi + (size_t)d * G4 * KCAT;
  const unsigned short* Bl_mat = Blo + (size_t)d * G4 * KCAT;

  float bval[4];
#pragma unroll
  for (int nt = 0; nt < 4; ++nt)
    bval[nt] = bias[d * G4 + n0 + wc * 64 + nt * 16 + r16];

  f32x4 acc[2][4];
#pragma unroll
  for (int mt = 0; mt < 2; ++mt)
#pragma unroll
    for (int nt = 0; nt < 4; ++nt) {
      f32x4 z = {0.f, 0.f, 0.f, 0.f};
      acc[mt][nt] = z;
    }

  // staging: 512 chunks of 8 elts per [128 x 32] tile; 1 chunk/thread
  const int rstg = tid >> 2;            // tile row 0..127
  const int ostg = (tid & 3) * 8;       // k offset 0/8/16/24

  for (int kt = 0; kt < KCAT / BK; ++kt) {
    const int k0 = kt * BK;

    // ---- global loads first (latency hiding) ----
    ushort8 bh0 = *(const ushort8*)(Bh_mat + (size_t)(n0 + rstg) * KCAT + k0 + ostg);
    ushort8 bl0 = *(const ushort8*)(Bl_mat + (size_t)(n0 + rstg) * KCAT + k0 + ostg);

    unsigned int pk[4];     // one-hot payload (8 k-values packed as 4 x uint32)
    ushort8 va0;            // bf16 A payload
    const bool onehot = (LAYER == 0) && (k0 < KIH);
    if (onehot) {
      const int* xr = x + (size_t)(m0 + rstg) * MAXLEN + k0 + ostg;
#pragma unroll
      for (int e = 0; e < 4; ++e) {
        int kk = k0 + ostg + 2 * e;
        int v0 = (kk < MAXLEN) ? xr[2 * e] : -1;
        int v1 = (kk + 1 < MAXLEN) ? xr[2 * e + 1] : -1;
        unsigned int lo = (v0 == tcur) ? 0x3F80u : 0u;   // bf16 1.0
        unsigned int hi = (v1 == tcur) ? 0x3F80u : 0u;
        pk[e] = lo | (hi << 16);
      }
    } else {
      const unsigned short* Asrc;
      int lda, kof;
      if (LAYER == 1 && k0 < KIH) {
        Asrc = seq_in + (size_t)tcur * B_SZ * (2 * H_SZ);
        lda = 2 * H_SZ; kof = k0;
      } else {
        Asrc = h_in + (size_t)d * B_SZ * H_SZ;
        lda = H_SZ; kof = k0 - KIH;
      }
      va0 = *(const ushort8*)(Asrc + (size_t)(m0 + rstg) * lda + kof + ostg);
    }

    __syncthreads();   // previous iteration's MFMA LDS reads complete

    if (onehot) {
      *(uint4*)(sm.t.A + rstg * LDSK + ostg) = make_uint4(pk[0], pk[1], pk[2], pk[3]);
    } else {
      *(ushort8*)(sm.t.A + rstg * LDSK + ostg) = va0;
    }
    *(ushort8*)(sm.t.Bh + rstg * LDSK + ostg) = bh0;
    *(ushort8*)(sm.t.Bl + rstg * LDSK + ostg) = bl0;
    __syncthreads();

    // ---- MFMA: 2x4 16x16 tiles per wave, 2 products (B hi+lo split) ----
    // A/B fragment: m/n = lane&15, k = (lane>>4)*8 + j   [m89/m91 verified]
    bf16x8 af[2], bh[4], bl[4];
#pragma unroll
    for (int mt = 0; mt < 2; ++mt)
      af[mt] = *(const bf16x8*)(sm.t.A + (wr * 32 + mt * 16 + r16) * LDSK + q * 8);
#pragma unroll
    for (int nt = 0; nt < 4; ++nt) {
      bh[nt] = *(const bf16x8*)(sm.t.Bh + (wc * 64 + nt * 16 + r16) * LDSK + q * 8);
      bl[nt] = *(const bf16x8*)(sm.t.Bl + (wc * 64 + nt * 16 + r16) * LDSK + q * 8);
    }
#pragma unroll
    for (int mt = 0; mt < 2; ++mt)
#pragma unroll
      for (int nt = 0; nt < 4; ++nt) {
        acc[mt][nt] = __builtin_amdgcn_mfma_f32_16x16x32_bf16(af[mt], bh[nt], acc[mt][nt], 0, 0, 0);
        acc[mt][nt] = __builtin_amdgcn_mfma_f32_16x16x32_bf16(af[mt], bl[nt], acc[mt][nt], 0, 0, 0);
      }
  }
  __syncthreads();   // all MFMA LDS reads done before gates scratch overwrite

  // ---- epilogue: 4 chunks of 32 gate-cols through 128x33 LDS scratch ----
  // C/D layout: col = lane&15, row = (lane>>4)*4 + reg   [m89/m91 verified]
  const int jbase = blockIdx.x * 32;   // 32 hidden units per N-block
  const float ew = (LAYER == 1) ? emb_w[tcur] : 0.f;

#pragma unroll
  for (int cc2 = 0; cc2 < 4; ++cc2) {
    if (wc == (cc2 >> 1)) {
      const int ntb = (cc2 & 1) * 2;
#pragma unroll
      for (int nti = 0; nti < 2; ++nti) {
        const int nt = ntb + nti;
#pragma unroll
        for (int mt = 0; mt < 2; ++mt)
#pragma unroll
          for (int r = 0; r < 4; ++r) {
            int ml = wr * 32 + mt * 16 + q * 4 + r;
            int nl = nti * 16 + r16;
            sm.gc[ml * GPAD + nl] = acc[mt][nt][r] + bval[nt];
          }
      }
    }
    __syncthreads();

    // read: 1024 cells (128 rows x 8 col-quads), 2 per thread
#pragma unroll
    for (int it = 0; it < 2; ++it) {
      int cell = it * 512 + tid;
      int rl = cell >> 3;        // row 0..127
      int jq = cell & 7;         // col-quad within chunk
      const float4 g = *(const float4*)(&sm.gc[rl * GPAD + jq * 4]);
      float si = sigmoidf_(g.x);
      float sf = sigmoidf_(g.y);
      float tg = tanhf_(g.z);
      float so = sigmoidf_(g.w);
      int b = m0 + rl;
      int j = jbase + cc2 * 8 + jq;
      size_t cidx = ((size_t)d * B_SZ + b) * H_SZ + j;
      float cn = sf * c_st[cidx] + si * tg;
      float hv = so * tanhf_(cn);
      c_st[cidx] = cn;
      h_out[cidx] = f2bf(hv);
      if (LAYER == 0) {
        seq_out[((size_t)tcur * B_SZ + b) * (2 * H_SZ) + d * H_SZ + j] = f2bf(hv);
      } else {
        zacc[(size_t)b * (2 * H_SZ) + d * H_SZ + j] += ew * hv;
      }
    }
    __syncthreads();
  }
}

// ============================================================
// final: z[b,:] = zacc[b,:] + emb_b ; out = z @ fc_w^T + fc_b   (all f32)
// ============================================================
__global__ __launch_bounds__(256)
void final_kernel(const float* __restrict__ zacc,    // [B, 2H] f32
                  const float* __restrict__ emb_b,   // [1]
                  const float* __restrict__ fc_w,    // [10, 2H]
                  const float* __restrict__ fc_b,    // [10]
                  float* __restrict__ out) {         // [B, 10] f32
  const int b = blockIdx.x;
  const int tid = threadIdx.x;
  const int c0 = tid * 4;

  const float zb = emb_b[0];
  const float4 z4 = *(const float4*)(zacc + (size_t)b * (2 * H_SZ) + c0);
  float z0 = z4.x + zb, z1 = z4.y + zb, z2 = z4.z + zb, z3 = z4.w + zb;

  float part[NCLS];
#pragma unroll
  for (int nc = 0; nc < NCLS; ++nc) {
    const float4 f = *(const float4*)(fc_w + (size_t)nc * (2 * H_SZ) + c0);
    part[nc] = z0 * f.x + z1 * f.y + z2 * f.z + z3 * f.w;
  }
#pragma unroll
  for (int nc = 0; nc < NCLS; ++nc)
#pragma unroll
    for (int off2 = 32; off2 > 0; off2 >>= 1)
      part[nc] += __shfl_down(part[nc], off2);

  __shared__ float red[4][NCLS];
  if ((tid & 63) == 0) {
#pragma unroll
    for (int nc = 0; nc < NCLS; ++nc) red[tid >> 6][nc] = part[nc];
  }
  __syncthreads();
  if (tid < NCLS) {
    float s = red[0][tid] + red[1][tid] + red[2][tid] + red[3][tid] + fc_b[tid];
    out[b * NCLS + tid] = s;
  }
}

// ============================================================
extern "C" void kernel_launch(void* const* d_in, const int* in_sizes, int n_in,
                              void* d_out, int out_size, void* d_ws, size_t ws_size,
                              hipStream_t stream) {
  (void)in_sizes; (void)n_in; (void)out_size; (void)ws_size;

  const int*   x     = (const int*)d_in[0];
  const float* w_ih0 = (const float*)d_in[1];
  const float* w_hh0 = (const float*)d_in[2];
  const float* b_ih0 = (const float*)d_in[3];
  const float* b_hh0 = (const float*)d_in[4];
  const float* w_ih1 = (const float*)d_in[5];
  const float* w_hh1 = (const float*)d_in[6];
  const float* b_ih1 = (const float*)d_in[7];
  const float* b_hh1 = (const float*)d_in[8];
  const float* emb_w = (const float*)d_in[9];
  const float* emb_b = (const float*)d_in[10];
  const float* fc_w  = (const float*)d_in[11];
  const float* fc_b  = (const float*)d_in[12];

  // -------- workspace layout (~165 MB) --------
  char* ws = (char*)d_ws;
  size_t off = 0;
  auto alloc = [&](size_t bytes) -> void* {
    void* p = ws + off;
    off += (bytes + 255) & ~(size_t)255;
    return p;
  };
  const size_t bmat_b = (size_t)2 * G4 * KCAT * 2;              // 12.6 MB each
  const size_t h_b    = (size_t)2 * B_SZ * H_SZ * 2;            // 4.2 MB
  const size_t c_b    = (size_t)2 * B_SZ * H_SZ * 4;            // 8.4 MB
  const size_t seq_b  = (size_t)TSTEPS * B_SZ * (2 * H_SZ) * 2; // 88 MB
  const size_t z_b    = (size_t)B_SZ * (2 * H_SZ) * 4;          // 8.4 MB

  unsigned short* Bhi0 = (unsigned short*)alloc(bmat_b);
  unsigned short* Blo0 = (unsigned short*)alloc(bmat_b);
  unsigned short* Bhi1 = (unsigned short*)alloc(bmat_b);
  unsigned short* Blo1 = (unsigned short*)alloc(bmat_b);
  float*          bias0 = (float*)alloc((size_t)2 * G4 * 4);
  float*          bias1 = (float*)alloc((size_t)2 * G4 * 4);
  unsigned short* hA    = (unsigned short*)alloc(h_b);
  unsigned short* hB    = (unsigned short*)alloc(h_b);
  float*          cst   = (float*)alloc(c_b);
  float*          zacc  = (float*)alloc(z_b);
  unsigned short* seq0  = (unsigned short*)alloc(seq_b);

  // -------- prep --------
  {
    size_t total = (size_t)2 * G4 * KCAT;
    int blocks = (int)((total + 255) / 256);
    prep_w_kernel<<<blocks, 256, 0, stream>>>(w_ih0, w_hh0, w_ih1, w_hh1,
                                              Bhi0, Blo0, Bhi1, Blo1);
    prep_b_kernel<<<16, 256, 0, stream>>>(b_ih0, b_hh0, b_ih1, b_hh1, bias0, bias1);
  }

  dim3 grid(G4 / BN, B_SZ / BM, 2);   // (16, 16, 2)

  // -------- layer 0 --------
  hipMemsetAsync(hA, 0, h_b, stream);
  hipMemsetAsync(cst, 0, c_b, stream);
  for (int s = 0; s < TSTEPS; ++s) {
    const unsigned short* hin  = (s & 1) ? hB : hA;
    unsigned short*       hout = (s & 1) ? hA : hB;
    step_kernel<0><<<grid, 512, 0, stream>>>(x, nullptr, Bhi0, Blo0, bias0, hin, hout, cst,
                                             seq0, nullptr, nullptr, s);
  }

  // -------- layer 1 (emb contraction fused into epilogue) --------
  hipMemsetAsync(hA, 0, h_b, stream);
  hipMemsetAsync(cst, 0, c_b, stream);
  hipMemsetAsync(zacc, 0, z_b, stream);
  for (int s = 0; s < TSTEPS; ++s) {
    const unsigned short* hin  = (s & 1) ? hB : hA;
    unsigned short*       hout = (s & 1) ? hA : hB;
    step_kernel<1><<<grid, 512, 0, stream>>>(nullptr, seq0, Bhi1, Blo1, bias1, hin, hout, cst,
                                             nullptr, zacc, emb_w, s);
  }

  // -------- fc --------
  final_kernel<<<B_SZ, 256, 0, stream>>>(zacc, emb_b, fc_w, fc_b, (float*)d_out);
}